// Round 1
// baseline (554.134 us; speedup 1.0000x reference)
//
#include <hip/hip_runtime.h>

#define N_NODES 100000
#define N_EDGESC 800000
#define NGRAPH 128
#define DIN 84
#define DHID 840
#define DF1 1024
#define DOUTC 384

typedef __attribute__((ext_vector_type(4))) float f32x4;
typedef __attribute__((ext_vector_type(8))) short bf16x8;

__device__ __forceinline__ unsigned short f2bf(float f) {
  union { float f; unsigned int u; } v; v.f = f;
  unsigned int r = v.u + 0x7FFFu + ((v.u >> 16) & 1u);
  return (unsigned short)(r >> 16);
}

// ---------------- CSR build ----------------
__global__ __launch_bounds__(256) void k_deg(const int* __restrict__ dst, int* __restrict__ deg) {
  int e = blockIdx.x * 256 + threadIdx.x;
  if (e >= N_EDGESC) return;
  atomicAdd(&deg[dst[e]], 1);
}

#define SCHUNK 1024
#define SBLOCKS 98   // ceil(100000/1024)

__global__ __launch_bounds__(256) void k_scan1(const int* __restrict__ deg, int* __restrict__ bsum) {
  __shared__ int sd[256];
  int b = blockIdx.x, t = threadIdx.x;
  int base = b * SCHUNK + t * 4;
  int s = 0;
  for (int j = 0; j < 4; j++) { int i = base + j; if (i < N_NODES) s += deg[i]; }
  sd[t] = s; __syncthreads();
  for (int off = 128; off > 0; off >>= 1) {
    if (t < off) sd[t] += sd[t + off];
    __syncthreads();
  }
  if (t == 0) bsum[b] = sd[0];
}

__global__ __launch_bounds__(128) void k_scan2(const int* __restrict__ bsum, int* __restrict__ boff) {
  __shared__ int sd[128];
  int t = threadIdx.x;
  int v = (t < SBLOCKS) ? bsum[t] : 0;
  sd[t] = v; __syncthreads();
  for (int off = 1; off < 128; off <<= 1) {
    int add = (t >= off) ? sd[t - off] : 0;
    __syncthreads();
    sd[t] += add;
    __syncthreads();
  }
  if (t < SBLOCKS) boff[t] = sd[t] - v;
}

__global__ __launch_bounds__(256) void k_scan3(const int* __restrict__ deg, const int* __restrict__ boff,
                                               int* __restrict__ rowptr, int* __restrict__ cursor) {
  __shared__ int sd[256];
  int b = blockIdx.x, t = threadIdx.x;
  int base = b * SCHUNK + t * 4;
  int v[4]; int s = 0;
  for (int j = 0; j < 4; j++) { int i = base + j; v[j] = (i < N_NODES) ? deg[i] : 0; s += v[j]; }
  sd[t] = s; __syncthreads();
  for (int off = 1; off < 256; off <<= 1) {
    int add = (t >= off) ? sd[t - off] : 0;
    __syncthreads();
    sd[t] += add;
    __syncthreads();
  }
  int run = sd[t] - s + boff[b];
  for (int j = 0; j < 4; j++) {
    int i = base + j;
    if (i < N_NODES) { rowptr[i] = run; cursor[i] = run; }
    run += v[j];
  }
  if (b == 0 && t == 0) rowptr[N_NODES] = N_EDGESC;
}

__global__ __launch_bounds__(256) void k_fill(const int* __restrict__ src, const int* __restrict__ dst,
                                              int* __restrict__ cursor, int* __restrict__ csr) {
  int e = blockIdx.x * 256 + threadIdx.x;
  if (e >= N_EDGESC) return;
  int d = dst[e];
  int pos = atomicAdd(&cursor[d], 1);
  csr[pos] = src[e];
}

// ---------------- per-graph node counts ----------------
__global__ __launch_bounds__(256) void k_counts(const int* __restrict__ batch, int* __restrict__ cnt) {
  __shared__ int h[NGRAPH];
  int t = threadIdx.x;
  if (t < NGRAPH) h[t] = 0;
  __syncthreads();
  int base = blockIdx.x * 2048;
  for (int j = 0; j < 8; j++) {
    int i = base + j * 256 + t;
    if (i < N_NODES) atomicAdd(&h[batch[i]], 1);
  }
  __syncthreads();
  if (t < NGRAPH && h[t] > 0) atomicAdd(&cnt[t], h[t]);
}

// ---------------- aggregation: out[i] = x[i] + sum_{e in in(i)} x[src_e]  ----------------
__global__ __launch_bounds__(256) void k_agg(const float* __restrict__ xin, const int* __restrict__ rowptr,
                                             const int* __restrict__ csr, float* __restrict__ out) {
  int node = blockIdx.x * 8 + (threadIdx.x >> 5);
  int lane = threadIdx.x & 31;
  if (node >= N_NODES) return;
  int r0 = rowptr[node], r1 = rowptr[node + 1];
  const f32x4* x4 = (const f32x4*)xin;
  f32x4 a = {0.f, 0.f, 0.f, 0.f};
  if (lane < 21) a = x4[node * 21 + lane];
  for (int e = r0; e < r1; e++) {
    int s = csr[e];
    if (lane < 21) a += x4[s * 21 + lane];
  }
  if (lane < 21) ((f32x4*)out)[node * 21 + lane] = a;
}

// ---------------- conv1: h1 = relu(agg @ W1 + b1), f32, W1 in LDS ----------------
__global__ __launch_bounds__(256) void k_conv1(const float* __restrict__ agg, const float* __restrict__ W1,
                                               const float* __restrict__ b1, float* __restrict__ h1) {
  __shared__ __align__(16) float w[DIN * DIN];
  __shared__ __align__(16) float bias[DIN];
  int t = threadIdx.x;
  for (int i = t; i < DIN * 21; i += 256) ((f32x4*)w)[i] = ((const f32x4*)W1)[i];
  if (t < DIN) bias[t] = b1[t];
  __syncthreads();
  int node = blockIdx.x * 256 + t;
  if (node >= N_NODES) return;
  f32x4 in4[21];
  for (int c = 0; c < 21; c++) in4[c] = ((const f32x4*)agg)[node * 21 + c];
  for (int p = 0; p < 3; p++) {
    f32x4 acc[7];
    #pragma unroll
    for (int c = 0; c < 7; c++) acc[c] = ((f32x4*)bias)[p * 7 + c];
    #pragma unroll
    for (int k4 = 0; k4 < 21; k4++) {
      f32x4 xv = in4[k4];
      #pragma unroll
      for (int kk = 0; kk < 4; kk++) {
        float x1 = xv[kk];
        #pragma unroll
        for (int c = 0; c < 7; c++) acc[c] += x1 * ((f32x4*)w)[(k4 * 4 + kk) * 21 + p * 7 + c];
      }
    }
    #pragma unroll
    for (int c = 0; c < 7; c++) {
      f32x4 r = acc[c];
      r.x = fmaxf(r.x, 0.f); r.y = fmaxf(r.y, 0.f); r.z = fmaxf(r.z, 0.f); r.w = fmaxf(r.w, 0.f);
      *(f32x4*)&h1[node * DIN + p * 28 + c * 4] = r;
    }
  }
}

// ---------------- W2^T in bf16, padded [896][96] ----------------
__global__ __launch_bounds__(256) void k_w2t(const float* __restrict__ W2, unsigned short* __restrict__ w2t) {
  int idx = blockIdx.x * 256 + threadIdx.x;
  if (idx >= 896 * 96) return;
  int n = idx / 96, k = idx % 96;
  float v = (n < DHID && k < DIN) ? W2[k * DHID + n] : 0.f;
  w2t[idx] = f2bf(v);
}

// ---------------- conv2 (bf16 MFMA) + fused max/mean pooling ----------------
__global__ __launch_bounds__(256) void k_conv2pool(const float* __restrict__ agg, const unsigned short* __restrict__ w2t,
                                                   const float* __restrict__ b2, const int* __restrict__ batch,
                                                   int* __restrict__ maxb, float* __restrict__ sump) {
  constexpr int LDA = 104;
  __shared__ __align__(16) unsigned short As[64 * LDA];
  __shared__ __align__(16) unsigned short Bs[64 * LDA];
  __shared__ int gb[64];
  __shared__ float pmax[256], psum[256];
  int t = threadIdx.x;
  int m0 = blockIdx.x * 64;

  for (int idx = t; idx < 64 * 21; idx += 256) {
    int r = idx / 21, c = idx - r * 21;
    int row = m0 + r;
    f32x4 v = {0.f, 0.f, 0.f, 0.f};
    if (row < N_NODES) v = *(const f32x4*)&agg[row * DIN + c * 4];
    unsigned int* p = (unsigned int*)&As[r * LDA + c * 4];
    p[0] = (unsigned int)f2bf(v.x) | ((unsigned int)f2bf(v.y) << 16);
    p[1] = (unsigned int)f2bf(v.z) | ((unsigned int)f2bf(v.w) << 16);
  }
  for (int idx = t; idx < 64 * 3; idx += 256) {
    int r = idx / 3, c = idx - r * 3;
    unsigned int* p = (unsigned int*)&As[r * LDA + 84 + c * 4];
    p[0] = 0; p[1] = 0;
  }
  if (t < 64) gb[t] = (m0 + t < N_NODES) ? batch[m0 + t] : -1;
  __syncthreads();

  int w = t >> 6, l = t & 63;
  int lr = l & 15, lk = (l >> 4) * 8;
  bf16x8 afr[3];
  #pragma unroll
  for (int kk = 0; kk < 3; kk++)
    afr[kk] = *(bf16x8*)&As[(w * 16 + lr) * LDA + lk + kk * 32];

  int gf = gb[w * 16], gl = gb[w * 16 + 15];
  bool waveUni = (gf == gl) && (gf >= 0);
  bool blockUni = (gb[0] == gb[63]) && (gb[63] >= 0);

  for (int nc = 0; nc < 14; nc++) {
    for (int idx = t; idx < 64 * 12; idx += 256) {
      int r = idx / 12, c = idx - r * 12;
      *(uint4*)&Bs[r * LDA + c * 8] = *(const uint4*)&w2t[(nc * 64 + r) * 96 + c * 8];
    }
    __syncthreads();
    #pragma unroll
    for (int nt = 0; nt < 4; nt++) {
      f32x4 acc = {0.f, 0.f, 0.f, 0.f};
      #pragma unroll
      for (int kk = 0; kk < 3; kk++) {
        bf16x8 bfr = *(bf16x8*)&Bs[(nt * 16 + lr) * LDA + lk + kk * 32];
        acc = __builtin_amdgcn_mfma_f32_16x16x32_bf16(afr[kk], bfr, acc, 0, 0, 0);
      }
      int c = nc * 64 + nt * 16 + lr;
      float bias = (c < DHID) ? b2[c] : 0.f;
      float v0 = fmaxf(acc.x + bias, 0.f);
      float v1 = fmaxf(acc.y + bias, 0.f);
      float v2 = fmaxf(acc.z + bias, 0.f);
      float v3 = fmaxf(acc.w + bias, 0.f);
      if (blockUni || waveUni) {
        float mx = fmaxf(fmaxf(v0, v1), fmaxf(v2, v3));
        float sm = (v0 + v1) + (v2 + v3);
        mx = fmaxf(mx, __shfl_xor(mx, 16)); sm += __shfl_xor(sm, 16);
        mx = fmaxf(mx, __shfl_xor(mx, 32)); sm += __shfl_xor(sm, 32);
        if (blockUni) {
          if (l < 16) { pmax[w * 64 + nt * 16 + l] = mx; psum[w * 64 + nt * 16 + l] = sm; }
        } else if (l < 16 && c < DHID) {
          atomicMax(&maxb[gf * DHID + c], __float_as_int(mx));
          atomicAdd(&sump[gf * DHID + c], sm);
        }
      } else {
        int rbase = w * 16 + (l >> 4) * 4;
        float vv[4] = {v0, v1, v2, v3};
        #pragma unroll
        for (int j = 0; j < 4; j++) {
          int g = gb[rbase + j];
          if (g >= 0 && c < DHID) {
            atomicMax(&maxb[g * DHID + c], __float_as_int(vv[j]));
            atomicAdd(&sump[g * DHID + c], vv[j]);
          }
        }
      }
    }
    __syncthreads();
    if (blockUni && t < 64) {
      int c = nc * 64 + t;
      if (c < DHID) {
        float mx = fmaxf(fmaxf(pmax[t], pmax[64 + t]), fmaxf(pmax[128 + t], pmax[192 + t]));
        float sm = (psum[t] + psum[64 + t]) + (psum[128 + t] + psum[192 + t]);
        int g = gb[0];
        atomicMax(&maxb[g * DHID + c], __float_as_int(mx));
        atomicAdd(&sump[g * DHID + c], sm);
      }
    }
  }
}

// ---------------- z = [maxp | meanp] ----------------
__global__ __launch_bounds__(256) void k_zprep(const int* __restrict__ maxb, const float* __restrict__ sump,
                                               const int* __restrict__ cnt, float* __restrict__ z) {
  int idx = blockIdx.x * 256 + threadIdx.x;
  if (idx >= NGRAPH * 2 * DHID) return;
  int g = idx / (2 * DHID), j = idx % (2 * DHID);
  int c = cnt[g];
  float v;
  if (j < DHID) v = (c > 0) ? __int_as_float(maxb[g * DHID + j]) : 0.f;
  else v = sump[g * DHID + (j - DHID)] / (float)max(c, 1);
  z[idx] = v;
}

// ---------------- MLP partial GEMM (f32, k-split, atomic accumulate) ----------------
template <int KTOT, int NTOT, int KC>
__global__ __launch_bounds__(256) void k_mlp(const float* __restrict__ Zin, const float* __restrict__ W,
                                             float* __restrict__ accout) {
  __shared__ float zt[128 * KC];
  int t = threadIdx.x;
  constexpr int NCH = NTOT / 64;
  int nc = blockIdx.x % NCH, kc = blockIdx.x / NCH;
  int k0 = kc * KC, n0 = nc * 64;
  for (int idx = t; idx < 128 * (KC / 4); idx += 256) {
    int r = idx / (KC / 4), c = idx % (KC / 4);
    *(f32x4*)&zt[r * KC + c * 4] = *(const f32x4*)&Zin[r * KTOT + k0 + c * 4];
  }
  __syncthreads();
  int nl = (t & 15) * 4, mg = t >> 4;
  f32x4 acc[8];
  #pragma unroll
  for (int mm = 0; mm < 8; mm++) acc[mm] = (f32x4){0.f, 0.f, 0.f, 0.f};
  #pragma unroll 4
  for (int k = 0; k < KC; k++) {
    f32x4 w4 = *(const f32x4*)&W[(k0 + k) * NTOT + n0 + nl];
    #pragma unroll
    for (int mm = 0; mm < 8; mm++) acc[mm] += zt[(mg * 8 + mm) * KC + k] * w4;
  }
  #pragma unroll
  for (int mm = 0; mm < 8; mm++)
    #pragma unroll
    for (int j = 0; j < 4; j++)
      atomicAdd(&accout[(mg * 8 + mm) * NTOT + n0 + nl + j], acc[mm][j]);
}

__global__ __launch_bounds__(256) void k_bias_relu(float* __restrict__ X, const float* __restrict__ b,
                                                   int NTOT, int total, int relu) {
  int i = blockIdx.x * 256 + threadIdx.x;
  if (i >= total) return;
  float v = X[i] + b[i % NTOT];
  X[i] = relu ? fmaxf(v, 0.f) : v;
}

// ---------------- launch ----------------
static constexpr size_t AL(size_t x) { return (x + 255) & ~(size_t)255; }

extern "C" void kernel_launch(void* const* d_in, const int* in_sizes, int n_in,
                              void* d_out, int out_size, void* d_ws, size_t ws_size,
                              hipStream_t stream) {
  const float* x   = (const float*)d_in[0];
  const int*  edge = (const int*)d_in[1];
  const int*  batch= (const int*)d_in[2];
  const float* W1  = (const float*)d_in[3];
  const float* b1  = (const float*)d_in[4];
  const float* W2  = (const float*)d_in[5];
  const float* b2  = (const float*)d_in[6];
  const float* Wg1 = (const float*)d_in[7];
  const float* bg1 = (const float*)d_in[8];
  const float* Wg2 = (const float*)d_in[9];
  const float* bg2 = (const float*)d_in[10];
  float* out = (float*)d_out;
  const int* src = edge;
  const int* dst = edge + N_EDGESC;

  size_t o = 0;
  size_t OFF_AGG = o;  o += AL((size_t)N_NODES * DIN * 4);
  size_t OFF_H1  = o;  o += AL((size_t)N_NODES * DIN * 4);
  size_t OFF_CSR = o;  o += AL((size_t)N_EDGESC * 4);
  size_t OFF_W2T = o;  o += AL((size_t)896 * 96 * 2);
  size_t OFF_RP  = o;  o += AL((size_t)(N_NODES + 1) * 4);
  size_t OFF_CUR = o;  o += AL((size_t)N_NODES * 4);
  size_t OFF_BS  = o;  o += AL(128 * 4);
  size_t OFF_BO  = o;  o += AL(128 * 4);
  size_t OFF_Z   = o;  o += AL((size_t)NGRAPH * 2 * DHID * 4);
  size_t OFF_DEG = o;  o += AL((size_t)N_NODES * 4);
  size_t OFF_MAX = o;  o += AL((size_t)NGRAPH * DHID * 4);
  size_t OFF_SUM = o;  o += AL((size_t)NGRAPH * DHID * 4);
  size_t OFF_CNT = o;  o += AL(NGRAPH * 4);
  size_t OFF_Z1  = o;  o += AL((size_t)NGRAPH * DF1 * 4);
  size_t TOTAL = o;
  size_t ZERO0 = OFF_DEG, ZEROB = TOTAL - OFF_DEG;
  if (ws_size < TOTAL) return;

  char* ws = (char*)d_ws;
  float* agg = (float*)(ws + OFF_AGG);
  float* h1  = (float*)(ws + OFF_H1);
  int* csr   = (int*)(ws + OFF_CSR);
  unsigned short* w2t = (unsigned short*)(ws + OFF_W2T);
  int* rowptr = (int*)(ws + OFF_RP);
  int* cursor = (int*)(ws + OFF_CUR);
  int* bsum  = (int*)(ws + OFF_BS);
  int* boff  = (int*)(ws + OFF_BO);
  float* z   = (float*)(ws + OFF_Z);
  int* deg   = (int*)(ws + OFF_DEG);
  int* maxb  = (int*)(ws + OFF_MAX);
  float* sump= (float*)(ws + OFF_SUM);
  int* cnt   = (int*)(ws + OFF_CNT);
  float* z1  = (float*)(ws + OFF_Z1);

  hipMemsetAsync(ws + ZERO0, 0, ZEROB, stream);
  hipMemsetAsync(d_out, 0, (size_t)out_size * 4, stream);

  k_w2t<<<(896 * 96 + 255) / 256, 256, 0, stream>>>(W2, w2t);
  k_deg<<<N_EDGESC / 256, 256, 0, stream>>>(dst, deg);
  k_scan1<<<SBLOCKS, 256, 0, stream>>>(deg, bsum);
  k_scan2<<<1, 128, 0, stream>>>(bsum, boff);
  k_scan3<<<SBLOCKS, 256, 0, stream>>>(deg, boff, rowptr, cursor);
  k_fill<<<N_EDGESC / 256, 256, 0, stream>>>(src, dst, cursor, csr);
  k_counts<<<(N_NODES + 2047) / 2048, 256, 0, stream>>>(batch, cnt);

  k_agg<<<(N_NODES + 7) / 8, 256, 0, stream>>>(x, rowptr, csr, agg);
  k_conv1<<<(N_NODES + 255) / 256, 256, 0, stream>>>(agg, W1, b1, h1);
  k_agg<<<(N_NODES + 7) / 8, 256, 0, stream>>>(h1, rowptr, csr, agg);
  k_conv2pool<<<(N_NODES + 63) / 64, 256, 0, stream>>>(agg, w2t, b2, batch, maxb, sump);

  k_zprep<<<(NGRAPH * 2 * DHID + 255) / 256, 256, 0, stream>>>(maxb, sump, cnt, z);
  k_mlp<2 * DHID, DF1, 120><<<(DF1 / 64) * (2 * DHID / 120), 256, 0, stream>>>(z, Wg1, z1);
  k_bias_relu<<<(NGRAPH * DF1 + 255) / 256, 256, 0, stream>>>(z1, bg1, DF1, NGRAPH * DF1, 1);
  k_mlp<DF1, DOUTC, 64><<<(DOUTC / 64) * (DF1 / 64), 256, 0, stream>>>(z1, Wg2, out);
  k_bias_relu<<<(NGRAPH * DOUTC + 255) / 256, 256, 0, stream>>>(out, bg2, DOUTC, NGRAPH * DOUTC, 0);
}

// Round 2
// 441.313 us; speedup vs baseline: 1.2557x; 1.2557x over previous
//
#include <hip/hip_runtime.h>

#define N_NODES 100000
#define N_EDGESC 800000
#define NGRAPH 128
#define DIN 84
#define DHID 840
#define DF1 1024
#define DOUTC 384

typedef __attribute__((ext_vector_type(4))) float f32x4;
typedef __attribute__((ext_vector_type(8))) short bf16x8;

__device__ __forceinline__ unsigned short f2bf(float f) {
  union { float f; unsigned int u; } v; v.f = f;
  unsigned int r = v.u + 0x7FFFu + ((v.u >> 16) & 1u);
  return (unsigned short)(r >> 16);
}
__device__ __forceinline__ float bf2f(unsigned short h) {
  union { unsigned int u; float f; } v; v.u = ((unsigned int)h) << 16;
  return v.f;
}

// ---------------- CSR build ----------------
__global__ __launch_bounds__(256) void k_deg(const int* __restrict__ dst, int* __restrict__ deg) {
  int e = blockIdx.x * 256 + threadIdx.x;
  if (e >= N_EDGESC) return;
  atomicAdd(&deg[dst[e]], 1);
}

#define SCHUNK 1024
#define SBLOCKS 98   // ceil(100000/1024)

__global__ __launch_bounds__(256) void k_scan1(const int* __restrict__ deg, int* __restrict__ bsum) {
  __shared__ int sd[256];
  int b = blockIdx.x, t = threadIdx.x;
  int base = b * SCHUNK + t * 4;
  int s = 0;
  for (int j = 0; j < 4; j++) { int i = base + j; if (i < N_NODES) s += deg[i]; }
  sd[t] = s; __syncthreads();
  for (int off = 128; off > 0; off >>= 1) {
    if (t < off) sd[t] += sd[t + off];
    __syncthreads();
  }
  if (t == 0) bsum[b] = sd[0];
}

__global__ __launch_bounds__(128) void k_scan2(const int* __restrict__ bsum, int* __restrict__ boff) {
  __shared__ int sd[128];
  int t = threadIdx.x;
  int v = (t < SBLOCKS) ? bsum[t] : 0;
  sd[t] = v; __syncthreads();
  for (int off = 1; off < 128; off <<= 1) {
    int add = (t >= off) ? sd[t - off] : 0;
    __syncthreads();
    sd[t] += add;
    __syncthreads();
  }
  if (t < SBLOCKS) boff[t] = sd[t] - v;
}

__global__ __launch_bounds__(256) void k_scan3(const int* __restrict__ deg, const int* __restrict__ boff,
                                               int* __restrict__ rowptr, int* __restrict__ cursor) {
  __shared__ int sd[256];
  int b = blockIdx.x, t = threadIdx.x;
  int base = b * SCHUNK + t * 4;
  int v[4]; int s = 0;
  for (int j = 0; j < 4; j++) { int i = base + j; v[j] = (i < N_NODES) ? deg[i] : 0; s += v[j]; }
  sd[t] = s; __syncthreads();
  for (int off = 1; off < 256; off <<= 1) {
    int add = (t >= off) ? sd[t - off] : 0;
    __syncthreads();
    sd[t] += add;
    __syncthreads();
  }
  int run = sd[t] - s + boff[b];
  for (int j = 0; j < 4; j++) {
    int i = base + j;
    if (i < N_NODES) { rowptr[i] = run; cursor[i] = run; }
    run += v[j];
  }
  if (b == 0 && t == 0) rowptr[N_NODES] = N_EDGESC;
}

__global__ __launch_bounds__(256) void k_fill(const int* __restrict__ src, const int* __restrict__ dst,
                                              int* __restrict__ cursor, int* __restrict__ csr) {
  int e = blockIdx.x * 256 + threadIdx.x;
  if (e >= N_EDGESC) return;
  int d = dst[e];
  int pos = atomicAdd(&cursor[d], 1);
  csr[pos] = src[e];
}

// ---------------- per-graph node counts ----------------
__global__ __launch_bounds__(256) void k_counts(const int* __restrict__ batch, int* __restrict__ cnt) {
  __shared__ int h[NGRAPH];
  int t = threadIdx.x;
  if (t < NGRAPH) h[t] = 0;
  __syncthreads();
  int base = blockIdx.x * 2048;
  for (int j = 0; j < 8; j++) {
    int i = base + j * 256 + t;
    if (i < N_NODES) atomicAdd(&h[batch[i]], 1);
  }
  __syncthreads();
  if (t < NGRAPH && h[t] > 0) atomicAdd(&cnt[t], h[t]);
}

// ---------------- aggregation: out[i] = x[i] + sum_{e in in(i)} x[src_e] ----------------
// 4-way edge unroll: batch independent csr loads then independent gathers (breaks
// the serial load->gather->load dependency chain; ~2-3x latency reduction).
__global__ __launch_bounds__(256) void k_agg(const float* __restrict__ xin, const int* __restrict__ rowptr,
                                             const int* __restrict__ csr, float* __restrict__ out) {
  int node = blockIdx.x * 8 + (threadIdx.x >> 5);
  int lane = threadIdx.x & 31;
  if (node >= N_NODES) return;
  int r0 = rowptr[node], r1 = rowptr[node + 1];
  const f32x4* x4 = (const f32x4*)xin;
  bool act = lane < 21;
  f32x4 a = {0.f, 0.f, 0.f, 0.f};
  if (act) a = x4[node * 21 + lane];
  int e = r0;
  for (; e + 4 <= r1; e += 4) {
    int s0 = csr[e], s1 = csr[e + 1], s2 = csr[e + 2], s3 = csr[e + 3];
    if (act) {
      f32x4 v0 = x4[s0 * 21 + lane];
      f32x4 v1 = x4[s1 * 21 + lane];
      f32x4 v2 = x4[s2 * 21 + lane];
      f32x4 v3 = x4[s3 * 21 + lane];
      a += (v0 + v1) + (v2 + v3);
    }
  }
  for (; e < r1; e++) {
    int s = csr[e];
    if (act) a += x4[s * 21 + lane];
  }
  if (act) ((f32x4*)out)[node * 21 + lane] = a;
}

// ---------------- W1^T split hi/lo bf16, padded [96][96] ----------------
__global__ __launch_bounds__(256) void k_w1t(const float* __restrict__ W1, unsigned short* __restrict__ w1h,
                                             unsigned short* __restrict__ w1l) {
  int idx = blockIdx.x * 256 + threadIdx.x;
  if (idx >= 96 * 96) return;
  int n = idx / 96, k = idx % 96;
  float v = (n < DIN && k < DIN) ? W1[k * DIN + n] : 0.f;
  unsigned short h = f2bf(v);
  w1h[idx] = h;
  w1l[idx] = f2bf(v - bf2f(h));
}

// ---------------- conv1 via MFMA, split-bf16 (hi*hi + lo*hi + hi*lo ~ f32 accuracy) --------
__global__ __launch_bounds__(256) void k_conv1m(const float* __restrict__ agg,
                                                const unsigned short* __restrict__ w1h,
                                                const unsigned short* __restrict__ w1l,
                                                const float* __restrict__ b1, float* __restrict__ h1) {
  constexpr int LDA = 104;
  __shared__ __align__(16) unsigned short Ah[64 * LDA];
  __shared__ __align__(16) unsigned short Al[64 * LDA];
  int t = threadIdx.x;
  int m0 = blockIdx.x * 64;

  for (int idx = t; idx < 64 * 21; idx += 256) {
    int r = idx / 21, c = idx - r * 21;
    int row = m0 + r;
    f32x4 v = {0.f, 0.f, 0.f, 0.f};
    if (row < N_NODES) v = *(const f32x4*)&agg[row * DIN + c * 4];
    unsigned short h0 = f2bf(v.x), h1_ = f2bf(v.y), h2_ = f2bf(v.z), h3_ = f2bf(v.w);
    unsigned short l0 = f2bf(v.x - bf2f(h0)), l1 = f2bf(v.y - bf2f(h1_));
    unsigned short l2 = f2bf(v.z - bf2f(h2_)), l3 = f2bf(v.w - bf2f(h3_));
    unsigned int* ph = (unsigned int*)&Ah[r * LDA + c * 4];
    ph[0] = (unsigned int)h0 | ((unsigned int)h1_ << 16);
    ph[1] = (unsigned int)h2_ | ((unsigned int)h3_ << 16);
    unsigned int* pl = (unsigned int*)&Al[r * LDA + c * 4];
    pl[0] = (unsigned int)l0 | ((unsigned int)l1 << 16);
    pl[1] = (unsigned int)l2 | ((unsigned int)l3 << 16);
  }
  for (int idx = t; idx < 64 * 6; idx += 256) {
    int r = idx / 6, c = idx - r * 6;
    ((unsigned int*)&Ah[r * LDA + 84])[c] = 0;
    ((unsigned int*)&Al[r * LDA + 84])[c] = 0;
  }
  __syncthreads();

  int w = t >> 6, l = t & 63;
  int lr = l & 15, lk = (l >> 4) * 8;
  bf16x8 ah[3], al[3];
  #pragma unroll
  for (int kk = 0; kk < 3; kk++) {
    ah[kk] = *(bf16x8*)&Ah[(w * 16 + lr) * LDA + lk + kk * 32];
    al[kk] = *(bf16x8*)&Al[(w * 16 + lr) * LDA + lk + kk * 32];
  }

  #pragma unroll
  for (int nt = 0; nt < 6; nt++) {
    f32x4 acc = {0.f, 0.f, 0.f, 0.f};
    #pragma unroll
    for (int kk = 0; kk < 3; kk++) {
      bf16x8 bh = *(const bf16x8*)&w1h[(nt * 16 + lr) * 96 + lk + kk * 32];
      bf16x8 bl = *(const bf16x8*)&w1l[(nt * 16 + lr) * 96 + lk + kk * 32];
      acc = __builtin_amdgcn_mfma_f32_16x16x32_bf16(ah[kk], bh, acc, 0, 0, 0);
      acc = __builtin_amdgcn_mfma_f32_16x16x32_bf16(al[kk], bh, acc, 0, 0, 0);
      acc = __builtin_amdgcn_mfma_f32_16x16x32_bf16(ah[kk], bl, acc, 0, 0, 0);
    }
    int col = nt * 16 + lr;
    if (col < DIN) {
      float bias = b1[col];
      int rbase = m0 + w * 16 + (l >> 4) * 4;
      #pragma unroll
      for (int j = 0; j < 4; j++) {
        if (rbase + j < N_NODES)
          h1[(rbase + j) * DIN + col] = fmaxf(acc[j] + bias, 0.f);
      }
    }
  }
}

// ---------------- W2^T in bf16, padded [896][96] ----------------
__global__ __launch_bounds__(256) void k_w2t(const float* __restrict__ W2, unsigned short* __restrict__ w2t) {
  int idx = blockIdx.x * 256 + threadIdx.x;
  if (idx >= 896 * 96) return;
  int n = idx / 96, k = idx % 96;
  float v = (n < DHID && k < DIN) ? W2[k * DHID + n] : 0.f;
  w2t[idx] = f2bf(v);
}

// ---------------- conv2 (bf16 MFMA) + fused max/mean pooling ----------------
__global__ __launch_bounds__(256) void k_conv2pool(const float* __restrict__ agg, const unsigned short* __restrict__ w2t,
                                                   const float* __restrict__ b2, const int* __restrict__ batch,
                                                   int* __restrict__ maxb, float* __restrict__ sump) {
  constexpr int LDA = 104;
  __shared__ __align__(16) unsigned short As[64 * LDA];
  __shared__ __align__(16) unsigned short Bs[64 * LDA];
  __shared__ int gb[64];
  __shared__ float pmax[256], psum[256];
  int t = threadIdx.x;
  int m0 = blockIdx.x * 64;

  for (int idx = t; idx < 64 * 21; idx += 256) {
    int r = idx / 21, c = idx - r * 21;
    int row = m0 + r;
    f32x4 v = {0.f, 0.f, 0.f, 0.f};
    if (row < N_NODES) v = *(const f32x4*)&agg[row * DIN + c * 4];
    unsigned int* p = (unsigned int*)&As[r * LDA + c * 4];
    p[0] = (unsigned int)f2bf(v.x) | ((unsigned int)f2bf(v.y) << 16);
    p[1] = (unsigned int)f2bf(v.z) | ((unsigned int)f2bf(v.w) << 16);
  }
  for (int idx = t; idx < 64 * 3; idx += 256) {
    int r = idx / 3, c = idx - r * 3;
    unsigned int* p = (unsigned int*)&As[r * LDA + 84 + c * 4];
    p[0] = 0; p[1] = 0;
  }
  if (t < 64) gb[t] = (m0 + t < N_NODES) ? batch[m0 + t] : -1;
  __syncthreads();

  int w = t >> 6, l = t & 63;
  int lr = l & 15, lk = (l >> 4) * 8;
  bf16x8 afr[3];
  #pragma unroll
  for (int kk = 0; kk < 3; kk++)
    afr[kk] = *(bf16x8*)&As[(w * 16 + lr) * LDA + lk + kk * 32];

  int gf = gb[w * 16], gl = gb[w * 16 + 15];
  bool waveUni = (gf == gl) && (gf >= 0);
  bool blockUni = (gb[0] == gb[63]) && (gb[63] >= 0);

  for (int nc = 0; nc < 14; nc++) {
    for (int idx = t; idx < 64 * 12; idx += 256) {
      int r = idx / 12, c = idx - r * 12;
      *(uint4*)&Bs[r * LDA + c * 8] = *(const uint4*)&w2t[(nc * 64 + r) * 96 + c * 8];
    }
    __syncthreads();
    #pragma unroll
    for (int nt = 0; nt < 4; nt++) {
      f32x4 acc = {0.f, 0.f, 0.f, 0.f};
      #pragma unroll
      for (int kk = 0; kk < 3; kk++) {
        bf16x8 bfr = *(bf16x8*)&Bs[(nt * 16 + lr) * LDA + lk + kk * 32];
        acc = __builtin_amdgcn_mfma_f32_16x16x32_bf16(afr[kk], bfr, acc, 0, 0, 0);
      }
      int c = nc * 64 + nt * 16 + lr;
      float bias = (c < DHID) ? b2[c] : 0.f;
      float v0 = fmaxf(acc.x + bias, 0.f);
      float v1 = fmaxf(acc.y + bias, 0.f);
      float v2 = fmaxf(acc.z + bias, 0.f);
      float v3 = fmaxf(acc.w + bias, 0.f);
      if (blockUni || waveUni) {
        float mx = fmaxf(fmaxf(v0, v1), fmaxf(v2, v3));
        float sm = (v0 + v1) + (v2 + v3);
        mx = fmaxf(mx, __shfl_xor(mx, 16)); sm += __shfl_xor(sm, 16);
        mx = fmaxf(mx, __shfl_xor(mx, 32)); sm += __shfl_xor(sm, 32);
        if (blockUni) {
          if (l < 16) { pmax[w * 64 + nt * 16 + l] = mx; psum[w * 64 + nt * 16 + l] = sm; }
        } else if (l < 16 && c < DHID) {
          atomicMax(&maxb[gf * DHID + c], __float_as_int(mx));
          atomicAdd(&sump[gf * DHID + c], sm);
        }
      } else {
        int rbase = w * 16 + (l >> 4) * 4;
        float vv[4] = {v0, v1, v2, v3};
        #pragma unroll
        for (int j = 0; j < 4; j++) {
          int g = gb[rbase + j];
          if (g >= 0 && c < DHID) {
            atomicMax(&maxb[g * DHID + c], __float_as_int(vv[j]));
            atomicAdd(&sump[g * DHID + c], vv[j]);
          }
        }
      }
    }
    __syncthreads();
    if (blockUni && t < 64) {
      int c = nc * 64 + t;
      if (c < DHID) {
        float mx = fmaxf(fmaxf(pmax[t], pmax[64 + t]), fmaxf(pmax[128 + t], pmax[192 + t]));
        float sm = (psum[t] + psum[64 + t]) + (psum[128 + t] + psum[192 + t]);
        int g = gb[0];
        atomicMax(&maxb[g * DHID + c], __float_as_int(mx));
        atomicAdd(&sump[g * DHID + c], sm);
      }
    }
  }
}

// ---------------- z = [maxp | meanp] ----------------
__global__ __launch_bounds__(256) void k_zprep(const int* __restrict__ maxb, const float* __restrict__ sump,
                                               const int* __restrict__ cnt, float* __restrict__ z) {
  int idx = blockIdx.x * 256 + threadIdx.x;
  if (idx >= NGRAPH * 2 * DHID) return;
  int g = idx / (2 * DHID), j = idx % (2 * DHID);
  int c = cnt[g];
  float v;
  if (j < DHID) v = (c > 0) ? __int_as_float(maxb[g * DHID + j]) : 0.f;
  else v = sump[g * DHID + (j - DHID)] / (float)max(c, 1);
  z[idx] = v;
}

// ---------------- MLP partial GEMM (f32, k-split, atomic accumulate) ----------------
template <int KTOT, int NTOT, int KC>
__global__ __launch_bounds__(256) void k_mlp(const float* __restrict__ Zin, const float* __restrict__ W,
                                             float* __restrict__ accout) {
  __shared__ float zt[128 * KC];
  int t = threadIdx.x;
  constexpr int NCH = NTOT / 64;
  int nc = blockIdx.x % NCH, kc = blockIdx.x / NCH;
  int k0 = kc * KC, n0 = nc * 64;
  for (int idx = t; idx < 128 * (KC / 4); idx += 256) {
    int r = idx / (KC / 4), c = idx % (KC / 4);
    *(f32x4*)&zt[r * KC + c * 4] = *(const f32x4*)&Zin[r * KTOT + k0 + c * 4];
  }
  __syncthreads();
  int nl = (t & 15) * 4, mg = t >> 4;
  f32x4 acc[8];
  #pragma unroll
  for (int mm = 0; mm < 8; mm++) acc[mm] = (f32x4){0.f, 0.f, 0.f, 0.f};
  #pragma unroll 4
  for (int k = 0; k < KC; k++) {
    f32x4 w4 = *(const f32x4*)&W[(k0 + k) * NTOT + n0 + nl];
    #pragma unroll
    for (int mm = 0; mm < 8; mm++) acc[mm] += zt[(mg * 8 + mm) * KC + k] * w4;
  }
  #pragma unroll
  for (int mm = 0; mm < 8; mm++)
    #pragma unroll
    for (int j = 0; j < 4; j++)
      atomicAdd(&accout[(mg * 8 + mm) * NTOT + n0 + nl + j], acc[mm][j]);
}

__global__ __launch_bounds__(256) void k_bias_relu(float* __restrict__ X, const float* __restrict__ b,
                                                   int NTOT, int total, int relu) {
  int i = blockIdx.x * 256 + threadIdx.x;
  if (i >= total) return;
  float v = X[i] + b[i % NTOT];
  X[i] = relu ? fmaxf(v, 0.f) : v;
}

// ---------------- launch ----------------
static constexpr size_t AL(size_t x) { return (x + 255) & ~(size_t)255; }

extern "C" void kernel_launch(void* const* d_in, const int* in_sizes, int n_in,
                              void* d_out, int out_size, void* d_ws, size_t ws_size,
                              hipStream_t stream) {
  const float* x   = (const float*)d_in[0];
  const int*  edge = (const int*)d_in[1];
  const int*  batch= (const int*)d_in[2];
  const float* W1  = (const float*)d_in[3];
  const float* b1  = (const float*)d_in[4];
  const float* W2  = (const float*)d_in[5];
  const float* b2  = (const float*)d_in[6];
  const float* Wg1 = (const float*)d_in[7];
  const float* bg1 = (const float*)d_in[8];
  const float* Wg2 = (const float*)d_in[9];
  const float* bg2 = (const float*)d_in[10];
  float* out = (float*)d_out;
  const int* src = edge;
  const int* dst = edge + N_EDGESC;

  size_t o = 0;
  size_t OFF_AGG = o;  o += AL((size_t)N_NODES * DIN * 4);
  size_t OFF_H1  = o;  o += AL((size_t)N_NODES * DIN * 4);
  size_t OFF_CSR = o;  o += AL((size_t)N_EDGESC * 4);
  size_t OFF_W2T = o;  o += AL((size_t)896 * 96 * 2);
  size_t OFF_W1H = o;  o += AL((size_t)96 * 96 * 2);
  size_t OFF_W1L = o;  o += AL((size_t)96 * 96 * 2);
  size_t OFF_RP  = o;  o += AL((size_t)(N_NODES + 1) * 4);
  size_t OFF_CUR = o;  o += AL((size_t)N_NODES * 4);
  size_t OFF_BS  = o;  o += AL(128 * 4);
  size_t OFF_BO  = o;  o += AL(128 * 4);
  size_t OFF_Z   = o;  o += AL((size_t)NGRAPH * 2 * DHID * 4);
  size_t OFF_DEG = o;  o += AL((size_t)N_NODES * 4);
  size_t OFF_MAX = o;  o += AL((size_t)NGRAPH * DHID * 4);
  size_t OFF_SUM = o;  o += AL((size_t)NGRAPH * DHID * 4);
  size_t OFF_CNT = o;  o += AL(NGRAPH * 4);
  size_t OFF_Z1  = o;  o += AL((size_t)NGRAPH * DF1 * 4);
  size_t TOTAL = o;
  size_t ZERO0 = OFF_DEG, ZEROB = TOTAL - OFF_DEG;
  if (ws_size < TOTAL) return;

  char* ws = (char*)d_ws;
  float* agg = (float*)(ws + OFF_AGG);
  float* h1  = (float*)(ws + OFF_H1);
  int* csr   = (int*)(ws + OFF_CSR);
  unsigned short* w2t = (unsigned short*)(ws + OFF_W2T);
  unsigned short* w1h = (unsigned short*)(ws + OFF_W1H);
  unsigned short* w1l = (unsigned short*)(ws + OFF_W1L);
  int* rowptr = (int*)(ws + OFF_RP);
  int* cursor = (int*)(ws + OFF_CUR);
  int* bsum  = (int*)(ws + OFF_BS);
  int* boff  = (int*)(ws + OFF_BO);
  float* z   = (float*)(ws + OFF_Z);
  int* deg   = (int*)(ws + OFF_DEG);
  int* maxb  = (int*)(ws + OFF_MAX);
  float* sump= (float*)(ws + OFF_SUM);
  int* cnt   = (int*)(ws + OFF_CNT);
  float* z1  = (float*)(ws + OFF_Z1);

  hipMemsetAsync(ws + ZERO0, 0, ZEROB, stream);
  hipMemsetAsync(d_out, 0, (size_t)out_size * 4, stream);

  k_w2t<<<(896 * 96 + 255) / 256, 256, 0, stream>>>(W2, w2t);
  k_w1t<<<(96 * 96 + 255) / 256, 256, 0, stream>>>(W1, w1h, w1l);
  k_deg<<<N_EDGESC / 256, 256, 0, stream>>>(dst, deg);
  k_scan1<<<SBLOCKS, 256, 0, stream>>>(deg, bsum);
  k_scan2<<<1, 128, 0, stream>>>(bsum, boff);
  k_scan3<<<SBLOCKS, 256, 0, stream>>>(deg, boff, rowptr, cursor);
  k_fill<<<N_EDGESC / 256, 256, 0, stream>>>(src, dst, cursor, csr);
  k_counts<<<(N_NODES + 2047) / 2048, 256, 0, stream>>>(batch, cnt);

  k_agg<<<(N_NODES + 7) / 8, 256, 0, stream>>>(x, rowptr, csr, agg);
  k_conv1m<<<(N_NODES + 63) / 64, 256, 0, stream>>>(agg, w1h, w1l, b1, h1);
  k_agg<<<(N_NODES + 7) / 8, 256, 0, stream>>>(h1, rowptr, csr, agg);
  k_conv2pool<<<(N_NODES + 63) / 64, 256, 0, stream>>>(agg, w2t, b2, batch, maxb, sump);

  k_zprep<<<(NGRAPH * 2 * DHID + 255) / 256, 256, 0, stream>>>(maxb, sump, cnt, z);
  k_mlp<2 * DHID, DF1, 120><<<(DF1 / 64) * (2 * DHID / 120), 256, 0, stream>>>(z, Wg1, z1);
  k_bias_relu<<<(NGRAPH * DF1 + 255) / 256, 256, 0, stream>>>(z1, bg1, DF1, NGRAPH * DF1, 1);
  k_mlp<DF1, DOUTC, 64><<<(DOUTC / 64) * (DF1 / 64), 256, 0, stream>>>(z1, Wg2, out);
  k_bias_relu<<<(NGRAPH * DOUTC + 255) / 256, 256, 0, stream>>>(out, bg2, DOUTC, NGRAPH * DOUTC, 0);
}